// Round 9
// baseline (107.893 us; speedup 1.0000x reference)
//
#include <hip/hip_runtime.h>

// MetricLoss: x[8192][128] f32 -> (loss_homo, loss_heter) f32.
// homo: exact per-group f32 algebra in prep (measured absmax 0.0).
// heter: LDS-staged bf16 32x32x16 MFMA Gram over flat triangular grid,
//        with last-block final reduction (no separate finalize dispatch).
// xb is stored PRE-SWIZZLED (slot s of row holds chunk s^(row&15)) so
// global_load_lds stages linearly and ds_read_b128 is conflict-spread (rule #21).
// Cross-block sums go through device-scope atomics (chunkSum RMW + counter);
// prep->heter visibility (xb, sq, homo_part, zeroed counters) rides the
// kernel-boundary release, same as xb always has.

#define DIM   128
#define NBT   64                  // 8192/128 tiles per dim
#define NTRI  2080                // NBT*(NBT+1)/2 upper-tri tiles
#define NPREP 512
#define NCHUNK 8                  // 2080 = 8 * 260 (XCD swizzle chunks)

typedef __bf16 bf16x8 __attribute__((ext_vector_type(8)));
typedef float  f32x16 __attribute__((ext_vector_type(16)));

__device__ __forceinline__ unsigned short f2bf(float f) {
  unsigned int u = __float_as_uint(f);
  u += 0x7fffu + ((u >> 16) & 1u);   // round-to-nearest-even
  return (unsigned short)(u >> 16);
}

__device__ __forceinline__ float wave_reduce(float v) {
#pragma unroll
  for (int off = 32; off > 0; off >>= 1) v += __shfl_xor(v, off);
  return v;
}

__device__ __forceinline__ void load_lds16(const void* g, void* l) {
  __builtin_amdgcn_global_load_lds(
      (const __attribute__((address_space(1))) void*)g,
      (__attribute__((address_space(3))) void*)l, 16, 0, 0);
}

// One wave per group of 4 rows. Phase A: norms + exact homo partial (lane=dim).
// Phase B: swizzled bf16 copy (lane = r*16+s; slot s gets chunk s^(row&15)).
// Block 0 additionally zeroes heter's atomics (runs strictly before heter).
__global__ __launch_bounds__(256) void prep_kernel(
    const float* __restrict__ x, unsigned short* __restrict__ xb,
    float* __restrict__ sq, float* __restrict__ homo_part,
    float* __restrict__ chunkSum, unsigned int* __restrict__ counter) {
  if (blockIdx.x == 0) {
    if (threadIdx.x < NCHUNK) chunkSum[threadIdx.x] = 0.f;
    if (threadIdx.x == NCHUNK) *counter = 0u;
  }
  const int wave = threadIdx.x >> 6;
  const int lane = threadIdx.x & 63;
  const int g = blockIdx.x * 4 + wave;           // 2048 groups
  float s0 = 0.f, s1 = 0.f, q = 0.f;
#pragma unroll
  for (int r = 0; r < 4; ++r) {
    const int row = g * 4 + r;
    const float v0 = x[row * DIM + lane];
    const float v1 = x[row * DIM + lane + 64];
    s0 += v0; s1 += v1;
    float rq = wave_reduce(v0 * v0 + v1 * v1);   // full row norm^2 (all lanes)
    if (lane == 0) sq[row] = rq;
    q += rq;
  }
  float ss = wave_reduce(s0 * s0 + s1 * s1);     // ||sum of 4 rows||^2
  __shared__ float hred[4];
  if (lane == 0) hred[wave] = 8.f * q - 2.f * ss;   // 2k*q - 2*ss, k=4

  // Phase B: swizzled vectorized bf16 write (x rows are L1/L2 hot from phase A)
  const int r = lane >> 4, s = lane & 15;
  const int row = g * 4 + r;
  const int c = s ^ (row & 15);                  // source chunk for slot s
  const float4* px = (const float4*)(x + row * DIM + c * 8);
  const float4 u0 = px[0], u1 = px[1];
  unsigned int p0 = (unsigned)f2bf(u0.x) | ((unsigned)f2bf(u0.y) << 16);
  unsigned int p1 = (unsigned)f2bf(u0.z) | ((unsigned)f2bf(u0.w) << 16);
  unsigned int p2 = (unsigned)f2bf(u1.x) | ((unsigned)f2bf(u1.y) << 16);
  unsigned int p3 = (unsigned)f2bf(u1.z) | ((unsigned)f2bf(u1.w) << 16);
  uint4 pk; pk.x = p0; pk.y = p1; pk.z = p2; pk.w = p3;
  *(uint4*)(xb + row * DIM + s * 8) = pk;        // linear 16B store, coalesced

  __syncthreads();
  if (threadIdx.x == 0)
    homo_part[blockIdx.x] = hred[0] + hred[1] + hred[2] + hred[3];
}

// Hinge epilogue over a wave's 2x2 of 32x32 fragments. DIAG => r0==c0 wave.
template<bool DIAG>
__device__ __forceinline__ float epilogue(const f32x16 (&acc)[2][2],
                                          const float* __restrict__ sq,
                                          int r0, int c0, int lc, int lk,
                                          float cj0, float cj1) {
  float hs = 0.f;
#pragma unroll
  for (int fi = 0; fi < 2; ++fi) {
#pragma unroll
    for (int r = 0; r < 16; ++r) {
      const int io = fi * 32 + (r & 3) + 8 * (r >> 2) + 4 * lk;  // C/D row offset
      const float si = sq[r0 + io];
#pragma unroll
      for (int fj = 0; fj < 2; ++fj) {
        if (DIAG && fi > fj) continue;           // fully-lower fragment
        float h = fmaxf(fmaf(2.f, acc[fi][fj][r], (fj ? cj1 : cj0) - si), 0.f);
        if (DIAG && fi == fj) {
          const int i = r0 + io;
          const int j = c0 + fj * 32 + lc;
          if (!((i >> 2) < (j >> 2))) h = 0.f;   // group mask on diagonal frags
        }
        hs += h;
      }
    }
  }
  return hs;
}

// Flat triangular grid (2080 blocks). 128x128 tile staged in LDS; 4 waves as
// 2x2 of 64x64 wave tiles, 32x32x16 bf16 MFMA from LDS. Last block reduces.
__global__ __launch_bounds__(256) void heter_kernel(
    const unsigned short* __restrict__ xb, const float* __restrict__ sq,
    const float* __restrict__ homo_part, float* __restrict__ chunkSum,
    unsigned int* __restrict__ counter, float* __restrict__ out) {
  __shared__ unsigned short ldsA[128 * DIM];     // 32 KB
  __shared__ unsigned short ldsB[128 * DIM];     // 32 KB

  // XCD swizzle (bijective: 2080 = 8*260) then triangular decode.
  const int chunk = blockIdx.x & 7;
  const int t = chunk * (NTRI / NCHUNK) + (blockIdx.x >> 3);
  int bi = (int)((129.0f - sqrtf(16641.0f - 8.0f * (float)t)) * 0.5f);
  bi = min(max(bi, 0), NBT - 1);
  while ((bi + 1) * NBT - ((bi + 1) * bi) / 2 <= t) ++bi;   // start(bi+1) <= t
  while (bi * NBT - (bi * (bi - 1)) / 2 > t) --bi;          // start(bi)   >  t
  const int bj = bi + (t - (bi * NBT - (bi * (bi - 1)) / 2));

  const int wave = threadIdx.x >> 6;
  const int lane = threadIdx.x & 63;

  // Stage both 128-row panels (xb already swizzled; linear copy).
  const unsigned short* gA = xb + bi * 128 * DIM;
  const unsigned short* gB = xb + bj * 128 * DIM;
#pragma unroll
  for (int i = 0; i < 8; ++i) {
    const int e = (wave * 32 + i * 4) * DIM;     // 4 rows (1 KB) per instr
    load_lds16(gA + e + lane * 8, &ldsA[e]);
    load_lds16(gB + e + lane * 8, &ldsB[e]);
  }
  __syncthreads();                                // drains vmcnt before barrier

  const int wi = wave >> 1, wj = wave & 1;
  const int lc = lane & 31;                       // A/B row within 32
  const int lk = lane >> 5;                       // k-half selector
  const bool diagBlock = (bi == bj);

  float hs = 0.f;
  if (!(diagBlock && wj < wi)) {                  // skip fully-lower wave tiles
    const int ra = (wi * 64 + lc) * DIM;
    const int rb = (wj * 64 + lc) * DIM;
    const int sl = lc & 15;

    f32x16 acc[2][2];
#pragma unroll
    for (int a = 0; a < 2; ++a)
#pragma unroll
      for (int b = 0; b < 2; ++b)
#pragma unroll
        for (int v = 0; v < 16; ++v) acc[a][b][v] = 0.f;

#pragma unroll
    for (int ks = 0; ks < 8; ++ks) {              // K=128 in steps of 16
      const int so = ((ks * 2 + lk) ^ sl) * 8;    // swizzled slot -> chunk ks*2+lk
      bf16x8 a0 = *(const bf16x8*)&ldsA[ra + so];
      bf16x8 a1 = *(const bf16x8*)&ldsA[ra + 32 * DIM + so];
      bf16x8 b0 = *(const bf16x8*)&ldsB[rb + so];
      bf16x8 b1 = *(const bf16x8*)&ldsB[rb + 32 * DIM + so];
      acc[0][0] = __builtin_amdgcn_mfma_f32_32x32x16_bf16(a0, b0, acc[0][0], 0, 0, 0);
      acc[0][1] = __builtin_amdgcn_mfma_f32_32x32x16_bf16(a0, b1, acc[0][1], 0, 0, 0);
      acc[1][0] = __builtin_amdgcn_mfma_f32_32x32x16_bf16(a1, b0, acc[1][0], 0, 0, 0);
      acc[1][1] = __builtin_amdgcn_mfma_f32_32x32x16_bf16(a1, b1, acc[1][1], 0, 0, 0);
    }

    const int r0 = bi * 128 + wi * 64;
    const int c0 = bj * 128 + wj * 64;
    const float cj0 = 1.f - sq[c0 + lc];
    const float cj1 = 1.f - sq[c0 + 32 + lc];
    const bool diagWave = diagBlock && (wi == wj);
    hs = diagWave ? epilogue<true>(acc, sq, r0, c0, lc, lk, cj0, cj1)
                  : epilogue<false>(acc, sq, r0, c0, lc, lk, cj0, cj1);
  }

  hs = wave_reduce(hs);
  __shared__ float red[4];
  __shared__ int lastFlag;
  if (lane == 0) red[wave] = hs;
  if (threadIdx.x == 0) lastFlag = 0;
  __syncthreads();
  if (threadIdx.x == 0) {
    const float blockSum = red[0] + red[1] + red[2] + red[3];
    atomicAdd(&chunkSum[chunk], blockSum);       // device-scope f32 RMW
    __threadfence();                             // chunkSum add completes first
    const unsigned int old = atomicAdd(counter, 1u);
    if (old == NTRI - 1) lastFlag = 1;           // we are the last block
  }
  __syncthreads();
  if (lastFlag) {
    // Final reduction: homo partials (kernel-boundary-safe normal loads) +
    // chunk sums (RMW-read at coherence point, immune to XCD L2 staleness).
    float hmo = 0.f;
    for (int i = threadIdx.x; i < NPREP; i += 256) hmo += homo_part[i];
    hmo = wave_reduce(hmo);
    __shared__ float fred[4];
    if (lane == 0) fred[wave] = hmo;
    __syncthreads();
    if (threadIdx.x == 0) {
      float s = 0.f;
#pragma unroll
      for (int k = 0; k < NCHUNK; ++k) s += atomicAdd(&chunkSum[k], 0.0f);
      out[0] = (fred[0] + fred[1] + fred[2] + fred[3]) / 24576.f;  // (B/k)*k*(k-1)
      out[1] = s / 33538048.f;                                     // C(2048,2)*16
    }
  }
}

extern "C" void kernel_launch(void* const* d_in, const int* in_sizes, int n_in,
                              void* d_out, int out_size, void* d_ws, size_t ws_size,
                              hipStream_t stream) {
  const float* x = (const float*)d_in[0];
  float* out = (float*)d_out;
  char* ws = (char*)d_ws;
  // ws layout (bytes): [0] chunkSum[8] (32 B)
  //                    [128] counter (4 B)
  //                    [2048] homo_part[512] (2 KB)
  //                    [10496] sq[8192] (32 KB)
  //                    [43264] xb bf16[8192*128] swizzled (2 MB)
  float* chunkSum      = (float*)(ws);
  unsigned int* counter = (unsigned int*)(ws + 128);
  float* homo_part     = (float*)(ws + 2048);
  float* sq            = (float*)(ws + 10496);
  unsigned short* xb   = (unsigned short*)(ws + 43264);

  hipLaunchKernelGGL(prep_kernel, dim3(NPREP), dim3(256), 0, stream,
                     x, xb, sq, homo_part, chunkSum, counter);
  hipLaunchKernelGGL(heter_kernel, dim3(NTRI), dim3(256), 0, stream,
                     xb, sq, homo_part, chunkSum, counter, out);
}

// Round 11
// 96.979 us; speedup vs baseline: 1.1125x; 1.1125x over previous
//
#include <hip/hip_runtime.h>

// MetricLoss: x[8192][128] f32 -> (loss_homo, loss_heter) f32.
// homo: exact per-group f32 algebra in prep (measured absmax 0.0).
// heter: LDS-staged bf16 32x32x16 MFMA Gram, 256x256 tiles, flat triangular
//        grid (528 blocks), 8 waves as 2x4 of 128x64 wave tiles.
// xb is stored PRE-SWIZZLED (slot s of row holds chunk s^(row&15)) so
// global_load_lds stages linearly and ds_read_b128 is conflict-spread (rule #21).
// R9 lesson: NO fused atomic tail (2080 same-cacheline RMWs + fences cost +34us).

#define DIM   128
#define NBT   32                  // 8192/256 tiles per dim
#define NTRI  528                 // NBT*(NBT+1)/2 upper-tri tiles (= 8*66)
#define NPREP 512

typedef __bf16 bf16x8 __attribute__((ext_vector_type(8)));
typedef float  f32x16 __attribute__((ext_vector_type(16)));

__device__ __forceinline__ unsigned short f2bf(float f) {
  unsigned int u = __float_as_uint(f);
  u += 0x7fffu + ((u >> 16) & 1u);   // round-to-nearest-even
  return (unsigned short)(u >> 16);
}

__device__ __forceinline__ float wave_reduce(float v) {
#pragma unroll
  for (int off = 32; off > 0; off >>= 1) v += __shfl_xor(v, off);
  return v;
}

__device__ __forceinline__ void load_lds16(const void* g, void* l) {
  __builtin_amdgcn_global_load_lds(
      (const __attribute__((address_space(1))) void*)g,
      (__attribute__((address_space(3))) void*)l, 16, 0, 0);
}

// One wave per group of 4 rows. Phase A: norms + exact homo partial (lane=dim).
// Phase B: swizzled bf16 copy (lane = r*16+s; slot s gets chunk s^(row&15)).
__global__ __launch_bounds__(256) void prep_kernel(
    const float* __restrict__ x, unsigned short* __restrict__ xb,
    float* __restrict__ sq, float* __restrict__ homo_part) {
  const int wave = threadIdx.x >> 6;
  const int lane = threadIdx.x & 63;
  const int g = blockIdx.x * 4 + wave;           // 2048 groups
  float s0 = 0.f, s1 = 0.f, q = 0.f;
#pragma unroll
  for (int r = 0; r < 4; ++r) {
    const int row = g * 4 + r;
    const float v0 = x[row * DIM + lane];
    const float v1 = x[row * DIM + lane + 64];
    s0 += v0; s1 += v1;
    float rq = wave_reduce(v0 * v0 + v1 * v1);   // full row norm^2 (all lanes)
    if (lane == 0) sq[row] = rq;
    q += rq;
  }
  float ss = wave_reduce(s0 * s0 + s1 * s1);     // ||sum of 4 rows||^2
  __shared__ float hred[4];
  if (lane == 0) hred[wave] = 8.f * q - 2.f * ss;   // 2k*q - 2*ss, k=4

  // Phase B: swizzled vectorized bf16 write (x rows are L1/L2 hot from phase A)
  const int r = lane >> 4, s = lane & 15;
  const int row = g * 4 + r;
  const int c = s ^ (row & 15);                  // source chunk for slot s
  const float4* px = (const float4*)(x + row * DIM + c * 8);
  const float4 u0 = px[0], u1 = px[1];
  unsigned int p0 = (unsigned)f2bf(u0.x) | ((unsigned)f2bf(u0.y) << 16);
  unsigned int p1 = (unsigned)f2bf(u0.z) | ((unsigned)f2bf(u0.w) << 16);
  unsigned int p2 = (unsigned)f2bf(u1.x) | ((unsigned)f2bf(u1.y) << 16);
  unsigned int p3 = (unsigned)f2bf(u1.z) | ((unsigned)f2bf(u1.w) << 16);
  uint4 pk; pk.x = p0; pk.y = p1; pk.z = p2; pk.w = p3;
  *(uint4*)(xb + row * DIM + s * 8) = pk;        // linear 16B store, coalesced

  __syncthreads();
  if (threadIdx.x == 0)
    homo_part[blockIdx.x] = hred[0] + hred[1] + hred[2] + hred[3];
}

// 256x256 tile staged in LDS (A:64KB + B:64KB), 8 waves as 2x4 of 128x64
// wave tiles, each 4x2 frags of 32x32x16 bf16 MFMA. Diag blocks read B=A.
__global__ __launch_bounds__(512, 2) void heter_kernel(
    const unsigned short* __restrict__ xb, const float* __restrict__ sq,
    float* __restrict__ partial) {
  __shared__ unsigned short ldsA[256 * DIM];     // 64 KB
  __shared__ unsigned short ldsB[256 * DIM];     // 64 KB

  // XCD swizzle (bijective: 528 = 8*66) then triangular decode.
  const int t = (blockIdx.x & 7) * (NTRI / 8) + (blockIdx.x >> 3);
  int bi = (int)((65.0f - sqrtf(4225.0f - 8.0f * (float)t)) * 0.5f);
  bi = min(max(bi, 0), NBT - 1);
  while ((bi + 1) * NBT - ((bi + 1) * bi) / 2 <= t) ++bi;   // start(bi+1) <= t
  while (bi * NBT - (bi * (bi - 1)) / 2 > t) --bi;          // start(bi)   >  t
  const int bj = bi + (t - (bi * NBT - (bi * (bi - 1)) / 2));

  const int wave = threadIdx.x >> 6;             // 0..7
  const int lane = threadIdx.x & 63;
  const bool diagBlock = (bi == bj);

  // Stage panels (xb already swizzled; linear copy). Diag: skip B (B==A).
  const unsigned short* gA = xb + bi * 256 * DIM;
  const unsigned short* gB = xb + bj * 256 * DIM;
#pragma unroll
  for (int i = 0; i < 8; ++i) {
    const int e = (wave * 32 + i * 4) * DIM;     // 4 rows (1 KB) per instr
    load_lds16(gA + e + lane * 8, &ldsA[e]);
    if (!diagBlock) load_lds16(gB + e + lane * 8, &ldsB[e]);
  }
  __syncthreads();                                // drains vmcnt before barrier
  const unsigned short* ldsBr = diagBlock ? ldsA : ldsB;

  const int wi = wave >> 2, wj = wave & 3;        // 2x4 wave grid
  const int lc = lane & 31;                       // A/B row within 32
  const int lk = lane >> 5;                       // k-half selector
  const int sl = lc & 15;

  float hs = 0.f;
  // Skip wave tiles fully below the diagonal (diag blocks: (1,0),(1,1)).
  if (!(diagBlock && (wj + 1) * 64 <= wi * 128)) {
    f32x16 acc[4][2];
#pragma unroll
    for (int a = 0; a < 4; ++a)
#pragma unroll
      for (int b = 0; b < 2; ++b)
#pragma unroll
        for (int v = 0; v < 16; ++v) acc[a][b][v] = 0.f;

#pragma unroll
    for (int ks = 0; ks < 8; ++ks) {              // K=128 in steps of 16
      const int so = ((ks * 2 + lk) ^ sl) * 8;    // swizzled slot -> chunk ks*2+lk
      bf16x8 a0 = *(const bf16x8*)&ldsA[(wi * 128 +  0 + lc) * DIM + so];
      bf16x8 a1 = *(const bf16x8*)&ldsA[(wi * 128 + 32 + lc) * DIM + so];
      bf16x8 a2 = *(const bf16x8*)&ldsA[(wi * 128 + 64 + lc) * DIM + so];
      bf16x8 a3 = *(const bf16x8*)&ldsA[(wi * 128 + 96 + lc) * DIM + so];
      bf16x8 b0 = *(const bf16x8*)&ldsBr[(wj * 64 +  0 + lc) * DIM + so];
      bf16x8 b1 = *(const bf16x8*)&ldsBr[(wj * 64 + 32 + lc) * DIM + so];
      acc[0][0] = __builtin_amdgcn_mfma_f32_32x32x16_bf16(a0, b0, acc[0][0], 0, 0, 0);
      acc[0][1] = __builtin_amdgcn_mfma_f32_32x32x16_bf16(a0, b1, acc[0][1], 0, 0, 0);
      acc[1][0] = __builtin_amdgcn_mfma_f32_32x32x16_bf16(a1, b0, acc[1][0], 0, 0, 0);
      acc[1][1] = __builtin_amdgcn_mfma_f32_32x32x16_bf16(a1, b1, acc[1][1], 0, 0, 0);
      acc[2][0] = __builtin_amdgcn_mfma_f32_32x32x16_bf16(a2, b0, acc[2][0], 0, 0, 0);
      acc[2][1] = __builtin_amdgcn_mfma_f32_32x32x16_bf16(a2, b1, acc[2][1], 0, 0, 0);
      acc[3][0] = __builtin_amdgcn_mfma_f32_32x32x16_bf16(a3, b0, acc[3][0], 0, 0, 0);
      acc[3][1] = __builtin_amdgcn_mfma_f32_32x32x16_bf16(a3, b1, acc[3][1], 0, 0, 0);
    }

    const int rbase = bi * 256 + wi * 128;        // global row of wave tile
    const int cbase = bj * 256 + wj * 64;         // global col of wave tile
    float cj0 = 1.f - sq[cbase + lc];
    float cj1 = 1.f - sq[cbase + 32 + lc];
#pragma unroll
    for (int fi = 0; fi < 4; ++fi) {
      const int frow = wi * 128 + fi * 32;        // tile-local frag row
#pragma unroll
      for (int r = 0; r < 16; ++r) {
        const int io = (r & 3) + 8 * (r >> 2) + 4 * lk;   // C/D row offset
        const int i = rbase + fi * 32 + io;
        const float si = sq[i];
#pragma unroll
        for (int fj = 0; fj < 2; ++fj) {
          const int fcol = wj * 64 + fj * 32;     // tile-local frag col
          if (diagBlock && fcol < frow) continue; // fully-lower frag (uniform)
          float h = fmaxf(fmaf(2.f, acc[fi][fj][r], (fj ? cj1 : cj0) - si), 0.f);
          if (diagBlock && fcol == frow) {
            const int j = cbase + fj * 32 + lc;
            if (!((i >> 2) < (j >> 2))) h = 0.f;  // group mask on diagonal frags
          }
          hs += h;
        }
      }
    }
  }

  hs = wave_reduce(hs);
  __shared__ float red[8];
  if (lane == 0) red[wave] = hs;
  __syncthreads();
  if (threadIdx.x == 0) {
    float bsum = 0.f;
#pragma unroll
    for (int w = 0; w < 8; ++w) bsum += red[w];
    partial[t] = bsum;
  }
}

__global__ __launch_bounds__(256) void finalize_kernel(
    const float* __restrict__ partial, const float* __restrict__ homo_part,
    float* __restrict__ out) {
  float s = 0.f, hmo = 0.f;
  for (int i = threadIdx.x; i < NTRI; i += 256) s += partial[i];
  for (int i = threadIdx.x; i < NPREP; i += 256) hmo += homo_part[i];
  s = wave_reduce(s);
  hmo = wave_reduce(hmo);
  __shared__ float red[4], hred[4];
  const int wave = threadIdx.x >> 6, lane = threadIdx.x & 63;
  if (lane == 0) { red[wave] = s; hred[wave] = hmo; }
  __syncthreads();
  if (threadIdx.x == 0) {
    out[0] = (hred[0] + hred[1] + hred[2] + hred[3]) / 24576.f;   // (B/k)*k*(k-1)
    out[1] = (red[0] + red[1] + red[2] + red[3]) / 33538048.f;    // C(2048,2)*16
  }
}

extern "C" void kernel_launch(void* const* d_in, const int* in_sizes, int n_in,
                              void* d_out, int out_size, void* d_ws, size_t ws_size,
                              hipStream_t stream) {
  const float* x = (const float*)d_in[0];
  float* out = (float*)d_out;
  char* ws = (char*)d_ws;
  // ws layout (bytes): [0] homo_part[512] (2 KB)
  //                    [2048] partial[528] (2112 B)
  //                    [10496] sq[8192] (32 KB)
  //                    [43264] xb bf16[8192*128] swizzled (2 MB)
  float* homo_part   = (float*)(ws);
  float* partial     = (float*)(ws + 2048);
  float* sq          = (float*)(ws + 10496);
  unsigned short* xb = (unsigned short*)(ws + 43264);

  hipLaunchKernelGGL(prep_kernel, dim3(NPREP), dim3(256), 0, stream, x, xb, sq, homo_part);
  hipLaunchKernelGGL(heter_kernel, dim3(NTRI), dim3(512), 0, stream, xb, sq, partial);
  hipLaunchKernelGGL(finalize_kernel, dim3(1), dim3(256), 0, stream, partial, homo_part, out);
}

// Round 14
// 79.581 us; speedup vs baseline: 1.3558x; 1.2186x over previous
//
#include <hip/hip_runtime.h>

// MetricLoss: x[8192][128] f32 -> (loss_homo, loss_heter) f32.
// homo: exact per-group f32 algebra in prep (measured absmax 0.0).
// heter v3: persistent-style all-resident pipeline. 1024 blocks (4/CU, all
//   resident), each sweeps 4-5 triangular jobs (128-row strip x 64-col B-tile).
//   A-slice in REGISTERS (per strip), B-tile double-buffered in LDS (16 KB),
//   stage(next) issued before compute(cur) -> stage hides under compute.
// R9 lesson: no fused atomic tail. R11 lesson: big tiles w/ 1 block/CU serialize.
// xb PRE-SWIZZLED (slot t of row holds chunk t^(row&15)) so global_load_lds
// stages linearly and ds_read_b128 is conflict-spread (rule #21).

#define DIM   128
#define NJOB  4160                // sum over strips s<64 of (128-2s)
#define NBLK  1024
#define NPREP 512

typedef __bf16 bf16x8 __attribute__((ext_vector_type(8)));
typedef float  f32x16 __attribute__((ext_vector_type(16)));

__device__ __forceinline__ unsigned short f2bf(float f) {
  unsigned int u = __float_as_uint(f);
  u += 0x7fffu + ((u >> 16) & 1u);   // round-to-nearest-even
  return (unsigned short)(u >> 16);
}

__device__ __forceinline__ float wave_reduce(float v) {
#pragma unroll
  for (int off = 32; off > 0; off >>= 1) v += __shfl_xor(v, off);
  return v;
}

__device__ __forceinline__ void load_lds16(const void* g, void* l) {
  __builtin_amdgcn_global_load_lds(
      (const __attribute__((address_space(1))) void*)g,
      (__attribute__((address_space(3))) void*)l, 16, 0, 0);
}

// One wave per group of 4 rows. Phase A: norms + exact homo partial (lane=dim).
// Phase B: swizzled bf16 copy (lane = r*16+s; slot s gets chunk s^(row&15)).
__global__ __launch_bounds__(256) void prep_kernel(
    const float* __restrict__ x, unsigned short* __restrict__ xb,
    float* __restrict__ sq, float* __restrict__ homo_part) {
  const int wave = threadIdx.x >> 6;
  const int lane = threadIdx.x & 63;
  const int g = blockIdx.x * 4 + wave;           // 2048 groups
  float s0 = 0.f, s1 = 0.f, q = 0.f;
#pragma unroll
  for (int r = 0; r < 4; ++r) {
    const int row = g * 4 + r;
    const float v0 = x[row * DIM + lane];
    const float v1 = x[row * DIM + lane + 64];
    s0 += v0; s1 += v1;
    float rq = wave_reduce(v0 * v0 + v1 * v1);   // full row norm^2 (all lanes)
    if (lane == 0) sq[row] = rq;
    q += rq;
  }
  float ss = wave_reduce(s0 * s0 + s1 * s1);     // ||sum of 4 rows||^2
  __shared__ float hred[4];
  if (lane == 0) hred[wave] = 8.f * q - 2.f * ss;   // 2k*q - 2*ss, k=4

  const int r = lane >> 4, sl = lane & 15;
  const int row = g * 4 + r;
  const int c = sl ^ (row & 15);                 // source chunk for slot sl
  const float4* px = (const float4*)(x + row * DIM + c * 8);
  const float4 u0 = px[0], u1 = px[1];
  unsigned int p0 = (unsigned)f2bf(u0.x) | ((unsigned)f2bf(u0.y) << 16);
  unsigned int p1 = (unsigned)f2bf(u0.z) | ((unsigned)f2bf(u0.w) << 16);
  unsigned int p2 = (unsigned)f2bf(u1.x) | ((unsigned)f2bf(u1.y) << 16);
  unsigned int p3 = (unsigned)f2bf(u1.z) | ((unsigned)f2bf(u1.w) << 16);
  uint4 pk; pk.x = p0; pk.y = p1; pk.z = p2; pk.w = p3;
  *(uint4*)(xb + row * DIM + sl * 8) = pk;       // linear 16B store, coalesced

  __syncthreads();
  if (threadIdx.x == 0)
    homo_part[blockIdx.x] = hred[0] + hred[1] + hred[2] + hred[3];
}

// Persistent-pipeline heter. Job j -> strip s (rows 128s..+127), B-tile c
// (cols 128s+64c..+63). start(s) = s*(129-s). 4 waves: wave w owns rows
// 32w..32w+31 (A in regs), full 64 cols (2 col-frags from LDS B).
__global__ __launch_bounds__(256, 4) void heter_kernel(
    const unsigned short* __restrict__ xb, const float* __restrict__ sq,
    float* __restrict__ partial) {
  __shared__ unsigned short Bl[2][64 * DIM];     // 2 x 16 KB

  const int wave = threadIdx.x >> 6;
  const int lane = threadIdx.x & 63;
  const int lc = lane & 31;                      // mfma row/col within 32
  const int lk = lane >> 5;                      // k-half selector
  const int sl = lc & 15;                        // swizzle key (rows 16-aligned)

  // Job range: XCD x gets contiguous 520 jobs; 128 blocks per XCD.
  const int x = blockIdx.x & 7, u = blockIdx.x >> 3;
  int j = x * 520 + 4 * u + min(u, 8);
  const int jend = j + ((u < 8) ? 5 : 4);

  // Decode first job -> (s, c).
  int s = (int)((129.0f - sqrtf(16641.0f - 4.0f * (float)j)) * 0.5f);
  s = min(max(s, 0), 63);
  while ((s + 1) * (129 - (s + 1)) <= j) ++s;
  while (s * (129 - s) > j) --s;
  int c = j - s * (129 - s);

  // A-slice of strip s into regs: rows 128s+32w+lc, all K (swizzled chunks).
  bf16x8 a[8];
  {
    const unsigned short* pA = xb + (128 * s + 32 * wave + lc) * DIM;
#pragma unroll
    for (int ks = 0; ks < 8; ++ks)
      a[ks] = *(const bf16x8*)(pA + (((2 * ks + lk) ^ sl) << 3));
  }

  // Prologue: stage first B-tile into buf 0.
  {
    const unsigned short* g = xb + (128 * s + 64 * c) * DIM;
#pragma unroll
    for (int i = 0; i < 4; ++i) {
      const int e = (wave * 16 + i * 4) * DIM;   // 4 rows (1 KB) per instr
      load_lds16(g + e + lane * 8, &Bl[0][e]);
    }
  }

  int buf = 0;
  float hs = 0.f;
  while (j < jend) {
    __syncthreads();                             // stage(buf) done; buf^1 free

    // Advance & issue next stage into buf^1 (overlaps with compute below).
    const int nj = j + 1;
    int ns = s, nc = c + 1;
    const bool havenext = (nj < jend);
    if (havenext) {
      if (nc >= 128 - 2 * ns) { ++ns; nc = 0; }  // strips all non-empty
      const unsigned short* g = xb + (128 * ns + 64 * nc) * DIM;
#pragma unroll
      for (int i = 0; i < 4; ++i) {
        const int e = (wave * 16 + i * 4) * DIM;
        load_lds16(g + e + lane * 8, &Bl[buf ^ 1][e]);
      }
    }

    // Compute current job from Bl[buf] with A regs.
    const unsigned short* bl = &Bl[buf][0];
    f32x16 acc0, acc1;
#pragma unroll
    for (int v = 0; v < 16; ++v) { acc0[v] = 0.f; acc1[v] = 0.f; }
#pragma unroll
    for (int ks = 0; ks < 8; ++ks) {
      const int so = (((2 * ks + lk) ^ sl) << 3);
      bf16x8 vb0 = *(const bf16x8*)&bl[(lc) * DIM + so];
      bf16x8 vb1 = *(const bf16x8*)&bl[(32 + lc) * DIM + so];
      acc0 = __builtin_amdgcn_mfma_f32_32x32x16_bf16(a[ks], vb0, acc0, 0, 0, 0);
      acc1 = __builtin_amdgcn_mfma_f32_32x32x16_bf16(a[ks], vb1, acc1, 0, 0, 0);
    }

    // Hinge epilogue. Frag cols: fc0 = 64c, fc1 = 64c+32 (tile-local);
    // wave rows fr = 32*wave. Below-diag frag -> 0; diag frag -> group mask.
    {
      const int fr = 32 * wave;
      const int cb = 128 * s + 64 * c;           // global col base
      const int rb = 128 * s + fr;               // global row base (this wave)
      const bool up0 = (64 * c >= fr), dg0 = (64 * c == fr);
      const bool up1 = (64 * c + 32 >= fr), dg1 = (64 * c + 32 == fr);
      const float cj0 = 1.f - sq[cb + lc];
      const float cj1 = 1.f - sq[cb + 32 + lc];
      const int jg0 = (cb + lc) >> 2, jg1 = (cb + 32 + lc) >> 2;
#pragma unroll
      for (int r = 0; r < 16; ++r) {
        const int io = (r & 3) + 8 * (r >> 2) + 4 * lk;  // C/D row offset
        const int i = rb + io;
        const int ig = i >> 2;
        const float si = sq[i];
        if (up0) {
          float h = fmaxf(fmaf(2.f, acc0[r], cj0 - si), 0.f);
          if (dg0 && !(ig < jg0)) h = 0.f;
          hs += h;
        }
        if (up1) {
          float h = fmaxf(fmaf(2.f, acc1[r], cj1 - si), 0.f);
          if (dg1 && !(ig < jg1)) h = 0.f;
          hs += h;
        }
      }
    }

    // Roll state; reload A regs on strip change (L2-hot, once or twice/block).
    if (havenext) {
      if (ns != s) {
        s = ns;
        const unsigned short* pA = xb + (128 * s + 32 * wave + lc) * DIM;
#pragma unroll
        for (int ks = 0; ks < 8; ++ks)
          a[ks] = *(const bf16x8*)(pA + (((2 * ks + lk) ^ sl) << 3));
      }
      c = nc;
      buf ^= 1;
    }
    j = nj;
  }

  hs = wave_reduce(hs);
  __shared__ float red[4];
  if (lane == 0) red[wave] = hs;
  __syncthreads();
  if (threadIdx.x == 0)
    partial[blockIdx.x] = red[0] + red[1] + red[2] + red[3];
}

__global__ __launch_bounds__(256) void finalize_kernel(
    const float* __restrict__ partial, const float* __restrict__ homo_part,
    float* __restrict__ out) {
  float s = 0.f, hmo = 0.f;
  for (int i = threadIdx.x; i < NBLK; i += 256) s += partial[i];
  for (int i = threadIdx.x; i < NPREP; i += 256) hmo += homo_part[i];
  s = wave_reduce(s);
  hmo = wave_reduce(hmo);
  __shared__ float red[4], hred[4];
  const int wave = threadIdx.x >> 6, lane = threadIdx.x & 63;
  if (lane == 0) { red[wave] = s; hred[wave] = hmo; }
  __syncthreads();
  if (threadIdx.x == 0) {
    out[0] = (hred[0] + hred[1] + hred[2] + hred[3]) / 24576.f;   // (B/k)*k*(k-1)
    out[1] = (red[0] + red[1] + red[2] + red[3]) / 33538048.f;    // C(2048,2)*16
  }
}

extern "C" void kernel_launch(void* const* d_in, const int* in_sizes, int n_in,
                              void* d_out, int out_size, void* d_ws, size_t ws_size,
                              hipStream_t stream) {
  const float* x = (const float*)d_in[0];
  float* out = (float*)d_out;
  char* ws = (char*)d_ws;
  // ws layout (bytes): [0] homo_part[512] (2 KB)
  //                    [2048] partial[1024] (4 KB)
  //                    [10496] sq[8192] (32 KB)
  //                    [43264] xb bf16[8192*128] swizzled (2 MB)
  float* homo_part   = (float*)(ws);
  float* partial     = (float*)(ws + 2048);
  float* sq          = (float*)(ws + 10496);
  unsigned short* xb = (unsigned short*)(ws + 43264);

  hipLaunchKernelGGL(prep_kernel, dim3(NPREP), dim3(256), 0, stream, x, xb, sq, homo_part);
  hipLaunchKernelGGL(heter_kernel, dim3(NBLK), dim3(256), 0, stream, xb, sq, partial);
  hipLaunchKernelGGL(finalize_kernel, dim3(1), dim3(256), 0, stream, partial, homo_part, out);
}